// Round 1
// baseline (150.599 us; speedup 1.0000x reference)
//
#include <hip/hip_runtime.h>
#include <cmath>

#define CT    1024   // C*T channels
#define PIX   1296   // 36*36 pixels
#define BATCH 16
#define NNEUR 4096
#define HW    36

// Kernel 1: transpose x [B, CT, 36, 36] -> feat [B, 1296, CT] so that a
// pixel's channel vector is contiguous (coalesced float4 gather in kernel 2).
__global__ __launch_bounds__(256) void transpose_kernel(
    const float* __restrict__ x, float* __restrict__ feat)
{
    __shared__ float tile[32][33];
    const int b      = blockIdx.z;
    const int pBase  = blockIdx.x * 32;
    const int ctBase = blockIdx.y * 32;
    const int tx = threadIdx.x;   // 0..31
    const int ty = threadIdx.y;   // 0..7
    const size_t xb = (size_t)b * CT * PIX;
#pragma unroll
    for (int i = 0; i < 4; ++i) {
        int p  = pBase + tx;
        int ct = ctBase + ty + i * 8;        // CT % 32 == 0, always valid
        if (p < PIX)
            tile[ty + i * 8][tx] = x[xb + (size_t)ct * PIX + p];
    }
    __syncthreads();
    const size_t fb = (size_t)b * PIX * CT;
#pragma unroll
    for (int i = 0; i < 4; ++i) {
        int p  = pBase + ty + i * 8;
        int ct = ctBase + tx;
        if (p < PIX)
            feat[fb + (size_t)p * CT + ct] = tile[tx][ty + i * 8];
    }
}

// Kernel 2: one block per neuron. 256 threads x 4 channels (float4).
// W-row fragment lives in registers across all batches/corners.
template <bool TR>
__global__ __launch_bounds__(256) void readout_kernel(
    const float* __restrict__ feat,   // TR: [B,1296,CT]   else raw x [B,CT,1296]
    const float* __restrict__ mu,     // [N,2]
    const float* __restrict__ Wm,     // [N,CT]
    const float* __restrict__ bias,   // [N]
    float* __restrict__ out)          // [B,N]
{
    const int n = blockIdx.x;
    const int t = threadIdx.x;

    const float4 w4 = reinterpret_cast<const float4*>(Wm + (size_t)n * CT)[t];

    // bilinear setup (align_corners=False, zeros padding), uniform per block
    float gx = fminf(fmaxf(mu[2 * n],     -1.f), 1.f);
    float gy = fminf(fmaxf(mu[2 * n + 1], -1.f), 1.f);
    float ix = (gx + 1.f) * (HW * 0.5f) - 0.5f;   // gx indexes W_in (inner dim)
    float iy = (gy + 1.f) * (HW * 0.5f) - 0.5f;   // gy indexes H_in
    float x0f = floorf(ix), y0f = floorf(iy);
    float wx1 = ix - x0f, wx0 = 1.f - wx1;
    float wy1 = iy - y0f, wy0 = 1.f - wy1;
    int x0 = (int)x0f, y0 = (int)y0f;

    float cw[4];
    int   cp[4];
#pragma unroll
    for (int k = 0; k < 4; ++k) {
        int xx = x0 + (k & 1), yy = y0 + (k >> 1);
        bool valid = (xx >= 0) && (xx < HW) && (yy >= 0) && (yy < HW);
        int xi = min(max(xx, 0), HW - 1), yi = min(max(yy, 0), HW - 1);
        cp[k] = yi * HW + xi;
        cw[k] = ((k & 1) ? wx1 : wx0) * ((k >> 1) ? wy1 : wy0) * (valid ? 1.f : 0.f);
    }

    float acc[BATCH];
#pragma unroll
    for (int b = 0; b < BATCH; ++b) {
        float s = 0.f;
#pragma unroll
        for (int k = 0; k < 4; ++k) {
            if (cw[k] != 0.f) {              // block-uniform branch, no divergence
                if (TR) {
                    const float4 v = reinterpret_cast<const float4*>(
                        feat + ((size_t)b * PIX + cp[k]) * CT)[t];
                    s += cw[k] * (v.x * w4.x + v.y * w4.y + v.z * w4.z + v.w * w4.w);
                } else {
                    const float* fp = feat + (size_t)b * CT * PIX + cp[k];
                    const int c0 = 4 * t;
                    float v0 = fp[(size_t)(c0 + 0) * PIX];
                    float v1 = fp[(size_t)(c0 + 1) * PIX];
                    float v2 = fp[(size_t)(c0 + 2) * PIX];
                    float v3 = fp[(size_t)(c0 + 3) * PIX];
                    s += cw[k] * (v0 * w4.x + v1 * w4.y + v2 * w4.z + v3 * w4.w);
                }
            }
        }
        acc[b] = s;
    }

    // reduce 256 partials per batch: wave shuffle, then cross-wave via LDS
#pragma unroll
    for (int b = 0; b < BATCH; ++b) {
        float v = acc[b];
#pragma unroll
        for (int off = 32; off > 0; off >>= 1)
            v += __shfl_down(v, off, 64);
        acc[b] = v;
    }
    __shared__ float red[4][BATCH];
    const int wave = t >> 6, lane = t & 63;
    if (lane == 0) {
#pragma unroll
        for (int b = 0; b < BATCH; ++b) red[wave][b] = acc[b];
    }
    __syncthreads();
    if (t < BATCH) {
        float y = red[0][t] + red[1][t] + red[2][t] + red[3][t] + bias[n];
        out[(size_t)t * NNEUR + n] = (y > 0.f) ? (y + 1.f) : expf(y);  // elu(y)+1
    }
}

extern "C" void kernel_launch(void* const* d_in, const int* in_sizes, int n_in,
                              void* d_out, int out_size, void* d_ws, size_t ws_size,
                              hipStream_t stream)
{
    const float* x    = (const float*)d_in[0];
    const float* mu   = (const float*)d_in[1];
    // d_in[2] = sigma, unused in eval mode
    const float* Wm   = (const float*)d_in[3];
    const float* bias = (const float*)d_in[4];
    float* out = (float*)d_out;

    const size_t featBytes = (size_t)BATCH * PIX * CT * sizeof(float);
    if (ws_size >= featBytes) {
        float* feat = (float*)d_ws;
        dim3 tg((PIX + 31) / 32, CT / 32, BATCH);
        transpose_kernel<<<tg, dim3(32, 8), 0, stream>>>(x, feat);
        readout_kernel<true><<<NNEUR, 256, 0, stream>>>(feat, mu, Wm, bias, out);
    } else {
        // workspace too small: correct (slow) strided path straight from x
        readout_kernel<false><<<NNEUR, 256, 0, stream>>>(x, mu, Wm, bias, out);
    }
}

// Round 2
// 89.991 us; speedup vs baseline: 1.6735x; 1.6735x over previous
//
#include <hip/hip_runtime.h>
#include <hip/hip_bf16.h>
#include <cmath>

#define CT    1024   // C*T channels
#define PIX   1296   // 36*36 pixels
#define BATCH 16
#define NNEUR 4096
#define HW    36

// ---------- Kernel 1: transpose + pack x [B,CT,36,36] f32 -> feat [B,1296,CT] bf16
__global__ __launch_bounds__(256) void transpose_bf16_kernel(
    const float* __restrict__ x, __hip_bfloat16* __restrict__ feat)
{
    __shared__ float tile[32][33];
    const int b      = blockIdx.z;
    const int pBase  = blockIdx.x * 32;
    const int ctBase = blockIdx.y * 32;
    const int tx = threadIdx.x;   // 0..31
    const int ty = threadIdx.y;   // 0..7
    const size_t xb = (size_t)b * CT * PIX;
#pragma unroll
    for (int i = 0; i < 4; ++i) {
        int p  = pBase + tx;
        int ct = ctBase + ty + i * 8;        // CT % 32 == 0, always valid
        if (p < PIX)
            tile[ty + i * 8][tx] = x[xb + (size_t)ct * PIX + p];
    }
    __syncthreads();
    const size_t fb = (size_t)b * PIX * CT;
#pragma unroll
    for (int i = 0; i < 4; ++i) {
        int p  = pBase + ty + i * 8;
        int ct = ctBase + tx;
        if (p < PIX)
            feat[fb + (size_t)p * CT + ct] = __float2bfloat16(tile[tx][ty + i * 8]);
    }
}

// ---------- Kernel 2: pack W [N,CT] f32 -> bf16
__global__ __launch_bounds__(256) void pack_w_kernel(
    const float* __restrict__ W, __hip_bfloat16* __restrict__ Wb)
{
    const int i = blockIdx.x * 256 + threadIdx.x;   // one float4 per thread
    const float4 v = reinterpret_cast<const float4*>(W)[i];
    __hip_bfloat16 o[4] = { __float2bfloat16(v.x), __float2bfloat16(v.y),
                            __float2bfloat16(v.z), __float2bfloat16(v.w) };
    reinterpret_cast<ushort4*>(Wb)[i] = *reinterpret_cast<ushort4*>(o);
}

__device__ __forceinline__ float bflo(unsigned u) { return __uint_as_float(u << 16); }
__device__ __forceinline__ float bfhi(unsigned u) { return __uint_as_float(u & 0xFFFF0000u); }

// ---------- Kernel 3: readout. Block = neuron. 256 threads =
// 128 channel-chunks (8 bf16 each) x 2 batch-groups (8 batches each).
__global__ __launch_bounds__(256) void readout_bf16_kernel(
    const __hip_bfloat16* __restrict__ feat,  // [B,1296,CT] bf16
    const float* __restrict__ mu,             // [N,2]
    const __hip_bfloat16* __restrict__ Wb,    // [N,CT] bf16
    const float* __restrict__ bias,           // [N]
    float* __restrict__ out)                  // [B,N]
{
    const int n = blockIdx.x;
    const int t = threadIdx.x;
    const int c = t & 127;   // channel-chunk: channels 8c..8c+7
    const int g = t >> 7;    // batch group: batches 8g..8g+7

    // W fragment -> 8 fp32 registers (reused for all 32 loads)
    const uint4 wv = reinterpret_cast<const uint4*>(Wb + (size_t)n * CT)[c];
    float w[8] = { bflo(wv.x), bfhi(wv.x), bflo(wv.y), bfhi(wv.y),
                   bflo(wv.z), bfhi(wv.z), bflo(wv.w), bfhi(wv.w) };

    // bilinear setup (align_corners=False, zeros padding), uniform per block
    float gx = fminf(fmaxf(mu[2 * n],     -1.f), 1.f);
    float gy = fminf(fmaxf(mu[2 * n + 1], -1.f), 1.f);
    float ix = (gx + 1.f) * (HW * 0.5f) - 0.5f;
    float iy = (gy + 1.f) * (HW * 0.5f) - 0.5f;
    float x0f = floorf(ix), y0f = floorf(iy);
    float wx1 = ix - x0f, wx0 = 1.f - wx1;
    float wy1 = iy - y0f, wy0 = 1.f - wy1;
    int x0 = (int)x0f, y0 = (int)y0f;

    float cw[4];
    int   cp[4];
#pragma unroll
    for (int k = 0; k < 4; ++k) {
        int xx = x0 + (k & 1), yy = y0 + (k >> 1);
        bool valid = (xx >= 0) && (xx < HW) && (yy >= 0) && (yy < HW);
        int xi = min(max(xx, 0), HW - 1), yi = min(max(yy, 0), HW - 1);
        cp[k] = yi * HW + xi;
        cw[k] = ((k & 1) ? wx1 : wx0) * ((k >> 1) ? wy1 : wy0) * (valid ? 1.f : 0.f);
    }

    float acc[8];
#pragma unroll
    for (int b8 = 0; b8 < 8; ++b8) {
        const int b = g * 8 + b8;
        float s = 0.f;
#pragma unroll
        for (int k = 0; k < 4; ++k) {
            if (cw[k] != 0.f) {              // block-uniform branch
                const uint4 v = reinterpret_cast<const uint4*>(
                    feat + ((size_t)b * PIX + cp[k]) * CT)[c];
                float d = bflo(v.x) * w[0];
                d = fmaf(bfhi(v.x), w[1], d);
                d = fmaf(bflo(v.y), w[2], d);
                d = fmaf(bfhi(v.y), w[3], d);
                d = fmaf(bflo(v.z), w[4], d);
                d = fmaf(bfhi(v.z), w[5], d);
                d = fmaf(bflo(v.w), w[6], d);
                d = fmaf(bfhi(v.w), w[7], d);
                s = fmaf(cw[k], d, s);
            }
        }
        acc[b8] = s;
    }

    // reduce 128 channel-chunks per (batch, group): wave shuffle then LDS
#pragma unroll
    for (int b8 = 0; b8 < 8; ++b8) {
        float v = acc[b8];
#pragma unroll
        for (int off = 32; off > 0; off >>= 1)
            v += __shfl_down(v, off, 64);
        acc[b8] = v;
    }
    __shared__ float red[4][8];
    const int wave = t >> 6, lane = t & 63;
    if (lane == 0) {
#pragma unroll
        for (int b8 = 0; b8 < 8; ++b8) red[wave][b8] = acc[b8];
    }
    __syncthreads();
    if (t < BATCH) {
        const int g2 = t >> 3, b8 = t & 7;
        float y = red[g2 * 2][b8] + red[g2 * 2 + 1][b8] + bias[n];
        out[(size_t)t * NNEUR + n] = (y > 0.f) ? (y + 1.f) : expf(y);  // elu(y)+1
    }
}

// ---------- fallback: fp32 strided path straight from x (ws too small)
__global__ __launch_bounds__(256) void readout_f32_strided_kernel(
    const float* __restrict__ x,      // [B,CT,1296]
    const float* __restrict__ mu,
    const float* __restrict__ Wm,
    const float* __restrict__ bias,
    float* __restrict__ out)
{
    const int n = blockIdx.x;
    const int t = threadIdx.x;
    const float4 w4 = reinterpret_cast<const float4*>(Wm + (size_t)n * CT)[t];

    float gx = fminf(fmaxf(mu[2 * n],     -1.f), 1.f);
    float gy = fminf(fmaxf(mu[2 * n + 1], -1.f), 1.f);
    float ix = (gx + 1.f) * (HW * 0.5f) - 0.5f;
    float iy = (gy + 1.f) * (HW * 0.5f) - 0.5f;
    float x0f = floorf(ix), y0f = floorf(iy);
    float wx1 = ix - x0f, wx0 = 1.f - wx1;
    float wy1 = iy - y0f, wy0 = 1.f - wy1;
    int x0 = (int)x0f, y0 = (int)y0f;

    float cw[4]; int cp[4];
#pragma unroll
    for (int k = 0; k < 4; ++k) {
        int xx = x0 + (k & 1), yy = y0 + (k >> 1);
        bool valid = (xx >= 0) && (xx < HW) && (yy >= 0) && (yy < HW);
        int xi = min(max(xx, 0), HW - 1), yi = min(max(yy, 0), HW - 1);
        cp[k] = yi * HW + xi;
        cw[k] = ((k & 1) ? wx1 : wx0) * ((k >> 1) ? wy1 : wy0) * (valid ? 1.f : 0.f);
    }

    float acc[BATCH];
#pragma unroll
    for (int b = 0; b < BATCH; ++b) {
        float s = 0.f;
#pragma unroll
        for (int k = 0; k < 4; ++k) {
            if (cw[k] != 0.f) {
                const float* fp = x + (size_t)b * CT * PIX + cp[k];
                const int c0 = 4 * t;
                s += cw[k] * (fp[(size_t)(c0 + 0) * PIX] * w4.x
                            + fp[(size_t)(c0 + 1) * PIX] * w4.y
                            + fp[(size_t)(c0 + 2) * PIX] * w4.z
                            + fp[(size_t)(c0 + 3) * PIX] * w4.w);
            }
        }
        acc[b] = s;
    }
#pragma unroll
    for (int b = 0; b < BATCH; ++b) {
        float v = acc[b];
#pragma unroll
        for (int off = 32; off > 0; off >>= 1)
            v += __shfl_down(v, off, 64);
        acc[b] = v;
    }
    __shared__ float red[4][BATCH];
    const int wave = t >> 6, lane = t & 63;
    if (lane == 0) {
#pragma unroll
        for (int b = 0; b < BATCH; ++b) red[wave][b] = acc[b];
    }
    __syncthreads();
    if (t < BATCH) {
        float y = red[0][t] + red[1][t] + red[2][t] + red[3][t] + bias[n];
        out[(size_t)t * NNEUR + n] = (y > 0.f) ? (y + 1.f) : expf(y);
    }
}

extern "C" void kernel_launch(void* const* d_in, const int* in_sizes, int n_in,
                              void* d_out, int out_size, void* d_ws, size_t ws_size,
                              hipStream_t stream)
{
    const float* x    = (const float*)d_in[0];
    const float* mu   = (const float*)d_in[1];
    // d_in[2] = sigma, unused in eval mode
    const float* Wm   = (const float*)d_in[3];
    const float* bias = (const float*)d_in[4];
    float* out = (float*)d_out;

    const size_t featBytes = (size_t)BATCH * PIX * CT * sizeof(__hip_bfloat16);
    const size_t wBytes    = (size_t)NNEUR * CT * sizeof(__hip_bfloat16);
    if (ws_size >= featBytes + wBytes) {
        __hip_bfloat16* feat = (__hip_bfloat16*)d_ws;
        __hip_bfloat16* Wb   = (__hip_bfloat16*)((char*)d_ws + featBytes);
        dim3 tg((PIX + 31) / 32, CT / 32, BATCH);
        transpose_bf16_kernel<<<tg, dim3(32, 8), 0, stream>>>(x, feat);
        pack_w_kernel<<<(NNEUR * CT / 4) / 256, 256, 0, stream>>>(Wm, Wb);
        readout_bf16_kernel<<<NNEUR, 256, 0, stream>>>(feat, mu, Wb, bias, out);
    } else {
        readout_f32_strided_kernel<<<NNEUR, 256, 0, stream>>>(x, mu, Wm, bias, out);
    }
}

// Round 3
// 75.003 us; speedup vs baseline: 2.0079x; 1.1998x over previous
//
#include <hip/hip_runtime.h>
#include <hip/hip_bf16.h>
#include <cmath>

#define CT    1024   // C*T channels
#define PIX   1296   // 36*36 pixels
#define BATCH 16
#define NNEUR 4096
#define HW    36
#define NBINS (HW * HW)

__device__ __forceinline__ unsigned short bfu(float f) {
    __hip_bfloat16 h = __float2bfloat16(f);
    return *reinterpret_cast<unsigned short*>(&h);
}
__device__ __forceinline__ float bflo(unsigned u) { return __uint_as_float(u << 16); }
__device__ __forceinline__ float bfhi(unsigned u) { return __uint_as_float(u & 0xFFFF0000u); }

// ---------- Kernel 1: transpose + pack x [B,CT,36,36] f32 -> feat [B,1296,CT] bf16
// Tile: 64 ct x 32 p. Stores are 16 B/lane packed bf16.
__global__ __launch_bounds__(256) void transpose_bf16_kernel(
    const float* __restrict__ x, __hip_bfloat16* __restrict__ feat)
{
    __shared__ unsigned short lds[64][34];   // [ct][p], pad to 34 to spread banks
    const int b      = blockIdx.z;
    const int ctBase = blockIdx.y * 64;
    const int pBase  = blockIdx.x * 32;
    const int t      = threadIdx.x;
    const size_t xb  = (size_t)b * CT * PIX;

    // load: 64 ct rows x 32 p; thread -> row = t/4, 8 p at (t%4)*8
    {
        const int r  = t >> 2;
        const int pc = (t & 3) * 8;
        const float* src = x + xb + (size_t)(ctBase + r) * PIX + pBase + pc;
        if (pBase + 32 <= PIX) {
            float4 a = reinterpret_cast<const float4*>(src)[0];
            float4 c = reinterpret_cast<const float4*>(src)[1];
            lds[r][pc + 0] = bfu(a.x); lds[r][pc + 1] = bfu(a.y);
            lds[r][pc + 2] = bfu(a.z); lds[r][pc + 3] = bfu(a.w);
            lds[r][pc + 4] = bfu(c.x); lds[r][pc + 5] = bfu(c.y);
            lds[r][pc + 6] = bfu(c.z); lds[r][pc + 7] = bfu(c.w);
        } else {
#pragma unroll
            for (int i = 0; i < 8; ++i) {
                int p = pBase + pc + i;
                lds[r][pc + i] = (p < PIX) ? bfu(src[i]) : (unsigned short)0;
            }
        }
    }
    __syncthreads();

    // store: 32 p rows x 64 ct; thread -> p = t/8, 8 ct at (t%8)*8, one 16B store
    const int pr = t >> 3;
    const int cc = (t & 7) * 8;
    if (pBase + pr < PIX) {
        unsigned short o[8];
#pragma unroll
        for (int i = 0; i < 8; ++i) o[i] = lds[cc + i][pr];
        const size_t off = (size_t)b * PIX * CT + (size_t)(pBase + pr) * CT + ctBase + cc;
        *reinterpret_cast<uint4*>((unsigned short*)feat + off) = *reinterpret_cast<uint4*>(o);
    }
}

// ---------- Kernel 2: counting sort of neurons by base pixel (single block).
// Output values don't depend on within-bin order, so LDS-atomic scatter is fine.
__global__ __launch_bounds__(1024) void sort_kernel(
    const float* __restrict__ mu, int* __restrict__ perm)
{
    __shared__ int hist[NBINS];
    __shared__ int chunkSum[48];
    const int t = threadIdx.x;
    for (int i = t; i < NBINS; i += 1024) hist[i] = 0;
    __syncthreads();

    int key[4];
#pragma unroll
    for (int j = 0; j < 4; ++j) {
        const int n = t + j * 1024;
        float gx = fminf(fmaxf(mu[2 * n],     -1.f), 1.f);
        float gy = fminf(fmaxf(mu[2 * n + 1], -1.f), 1.f);
        float ix = (gx + 1.f) * (HW * 0.5f) - 0.5f;
        float iy = (gy + 1.f) * (HW * 0.5f) - 0.5f;
        int xi = min(max((int)floorf(ix), 0), HW - 1);
        int yi = min(max((int)floorf(iy), 0), HW - 1);
        key[j] = yi * HW + xi;
        atomicAdd(&hist[key[j]], 1);
    }
    __syncthreads();

    // two-level exclusive scan over 1296 bins: 41 chunks x 32
    if (t < 41) {
        int s = 0;
        for (int i = 0; i < 32; ++i) {
            int idx = t * 32 + i;
            if (idx < NBINS) s += hist[idx];
        }
        chunkSum[t] = s;
    }
    __syncthreads();
    if (t == 0) {
        int run = 0;
        for (int i = 0; i < 41; ++i) { int v = chunkSum[i]; chunkSum[i] = run; run += v; }
    }
    __syncthreads();
    if (t < 41) {
        int run = chunkSum[t];
        for (int i = 0; i < 32; ++i) {
            int idx = t * 32 + i;
            if (idx < NBINS) { int v = hist[idx]; hist[idx] = run; run += v; }
        }
    }
    __syncthreads();

#pragma unroll
    for (int j = 0; j < 4; ++j) {
        const int n = t + j * 1024;
        const int pos = atomicAdd(&hist[key[j]], 1);
        perm[pos] = n;
    }
}

// ---------- Kernel 3: readout. Block = sorted neuron (chunked XCD swizzle).
// 256 threads = 128 channel-chunks (8 bf16) x 2 batch-groups (8 batches).
__global__ __launch_bounds__(256) void readout_bf16_kernel(
    const __hip_bfloat16* __restrict__ feat,  // [B,1296,CT] bf16
    const float* __restrict__ mu,             // [N,2]
    const float* __restrict__ Wm,             // [N,CT] fp32
    const float* __restrict__ bias,           // [N]
    const int* __restrict__ perm,             // [N] pixel-sorted neuron ids
    float* __restrict__ out)                  // [B,N]
{
    const int bid    = blockIdx.x;
    const int sorted = (bid & 7) * (NNEUR / 8) + (bid >> 3);  // XCD-chunked
    const int n      = perm[sorted];
    const int t = threadIdx.x;
    const int c = t & 127;   // channel-chunk: channels 8c..8c+7
    const int g = t >> 7;    // batch group: batches 8g..8g+7

    // W fragment (fp32) -> 8 registers, reused for all 32 feat loads
    const float4 wa = reinterpret_cast<const float4*>(Wm + (size_t)n * CT)[2 * c];
    const float4 wb = reinterpret_cast<const float4*>(Wm + (size_t)n * CT)[2 * c + 1];
    const float w[8] = { wa.x, wa.y, wa.z, wa.w, wb.x, wb.y, wb.z, wb.w };

    // bilinear setup (align_corners=False, zeros padding), uniform per block
    float gx = fminf(fmaxf(mu[2 * n],     -1.f), 1.f);
    float gy = fminf(fmaxf(mu[2 * n + 1], -1.f), 1.f);
    float ix = (gx + 1.f) * (HW * 0.5f) - 0.5f;
    float iy = (gy + 1.f) * (HW * 0.5f) - 0.5f;
    float x0f = floorf(ix), y0f = floorf(iy);
    float wx1 = ix - x0f, wx0 = 1.f - wx1;
    float wy1 = iy - y0f, wy0 = 1.f - wy1;
    int x0 = (int)x0f, y0 = (int)y0f;

    float cw[4];
    int   cp[4];
#pragma unroll
    for (int k = 0; k < 4; ++k) {
        int xx = x0 + (k & 1), yy = y0 + (k >> 1);
        bool valid = (xx >= 0) && (xx < HW) && (yy >= 0) && (yy < HW);
        int xi = min(max(xx, 0), HW - 1), yi = min(max(yy, 0), HW - 1);
        cp[k] = yi * HW + xi;
        cw[k] = ((k & 1) ? wx1 : wx0) * ((k >> 1) ? wy1 : wy0) * (valid ? 1.f : 0.f);
    }

    float acc[8];
#pragma unroll
    for (int b8 = 0; b8 < 8; ++b8) {
        const int b = g * 8 + b8;
        float s = 0.f;
#pragma unroll
        for (int k = 0; k < 4; ++k) {   // unconditional: zero weight kills invalid
            const uint4 v = reinterpret_cast<const uint4*>(
                feat + ((size_t)b * PIX + cp[k]) * CT)[c];
            float d = bflo(v.x) * w[0];
            d = fmaf(bfhi(v.x), w[1], d);
            d = fmaf(bflo(v.y), w[2], d);
            d = fmaf(bfhi(v.y), w[3], d);
            d = fmaf(bflo(v.z), w[4], d);
            d = fmaf(bfhi(v.z), w[5], d);
            d = fmaf(bflo(v.w), w[6], d);
            d = fmaf(bfhi(v.w), w[7], d);
            s = fmaf(cw[k], d, s);
        }
        acc[b8] = s;
    }

    // reduce 128 channel-chunks per (batch, group): wave shuffle then LDS
#pragma unroll
    for (int b8 = 0; b8 < 8; ++b8) {
        float v = acc[b8];
#pragma unroll
        for (int off = 32; off > 0; off >>= 1)
            v += __shfl_down(v, off, 64);
        acc[b8] = v;
    }
    __shared__ float red[4][8];
    const int wave = t >> 6, lane = t & 63;
    if (lane == 0) {
#pragma unroll
        for (int b8 = 0; b8 < 8; ++b8) red[wave][b8] = acc[b8];
    }
    __syncthreads();
    if (t < BATCH) {
        const int g2 = t >> 3, b8 = t & 7;
        float y = red[g2 * 2][b8] + red[g2 * 2 + 1][b8] + bias[n];
        out[(size_t)t * NNEUR + n] = (y > 0.f) ? (y + 1.f) : expf(y);  // elu(y)+1
    }
}

// ---------- fallback: fp32 strided path straight from x (ws too small)
__global__ __launch_bounds__(256) void readout_f32_strided_kernel(
    const float* __restrict__ x,      // [B,CT,1296]
    const float* __restrict__ mu,
    const float* __restrict__ Wm,
    const float* __restrict__ bias,
    float* __restrict__ out)
{
    const int n = blockIdx.x;
    const int t = threadIdx.x;
    const float4 w4 = reinterpret_cast<const float4*>(Wm + (size_t)n * CT)[t];

    float gx = fminf(fmaxf(mu[2 * n],     -1.f), 1.f);
    float gy = fminf(fmaxf(mu[2 * n + 1], -1.f), 1.f);
    float ix = (gx + 1.f) * (HW * 0.5f) - 0.5f;
    float iy = (gy + 1.f) * (HW * 0.5f) - 0.5f;
    float x0f = floorf(ix), y0f = floorf(iy);
    float wx1 = ix - x0f, wx0 = 1.f - wx1;
    float wy1 = iy - y0f, wy0 = 1.f - wy1;
    int x0 = (int)x0f, y0 = (int)y0f;

    float cw[4]; int cp[4];
#pragma unroll
    for (int k = 0; k < 4; ++k) {
        int xx = x0 + (k & 1), yy = y0 + (k >> 1);
        bool valid = (xx >= 0) && (xx < HW) && (yy >= 0) && (yy < HW);
        int xi = min(max(xx, 0), HW - 1), yi = min(max(yy, 0), HW - 1);
        cp[k] = yi * HW + xi;
        cw[k] = ((k & 1) ? wx1 : wx0) * ((k >> 1) ? wy1 : wy0) * (valid ? 1.f : 0.f);
    }

    float acc[BATCH];
#pragma unroll
    for (int b = 0; b < BATCH; ++b) {
        float s = 0.f;
#pragma unroll
        for (int k = 0; k < 4; ++k) {
            if (cw[k] != 0.f) {
                const float* fp = x + (size_t)b * CT * PIX + cp[k];
                const int c0 = 4 * t;
                s += cw[k] * (fp[(size_t)(c0 + 0) * PIX] * w4.x
                            + fp[(size_t)(c0 + 1) * PIX] * w4.y
                            + fp[(size_t)(c0 + 2) * PIX] * w4.z
                            + fp[(size_t)(c0 + 3) * PIX] * w4.w);
            }
        }
        acc[b] = s;
    }
#pragma unroll
    for (int b = 0; b < BATCH; ++b) {
        float v = acc[b];
#pragma unroll
        for (int off = 32; off > 0; off >>= 1)
            v += __shfl_down(v, off, 64);
        acc[b] = v;
    }
    __shared__ float red[4][BATCH];
    const int wave = t >> 6, lane = t & 63;
    if (lane == 0) {
#pragma unroll
        for (int b = 0; b < BATCH; ++b) red[wave][b] = acc[b];
    }
    __syncthreads();
    if (t < BATCH) {
        float y = red[0][t] + red[1][t] + red[2][t] + red[3][t] + bias[n];
        out[(size_t)t * NNEUR + n] = (y > 0.f) ? (y + 1.f) : expf(y);
    }
}

extern "C" void kernel_launch(void* const* d_in, const int* in_sizes, int n_in,
                              void* d_out, int out_size, void* d_ws, size_t ws_size,
                              hipStream_t stream)
{
    const float* x    = (const float*)d_in[0];
    const float* mu   = (const float*)d_in[1];
    // d_in[2] = sigma, unused in eval mode
    const float* Wm   = (const float*)d_in[3];
    const float* bias = (const float*)d_in[4];
    float* out = (float*)d_out;

    const size_t featBytes = (size_t)BATCH * PIX * CT * sizeof(__hip_bfloat16);
    const size_t permBytes = (size_t)NNEUR * sizeof(int);
    if (ws_size >= featBytes + permBytes) {
        __hip_bfloat16* feat = (__hip_bfloat16*)d_ws;
        int* perm = (int*)((char*)d_ws + featBytes);
        dim3 tg((PIX + 31) / 32, CT / 64, BATCH);
        transpose_bf16_kernel<<<tg, 256, 0, stream>>>(x, feat);
        sort_kernel<<<1, 1024, 0, stream>>>(mu, perm);
        readout_bf16_kernel<<<NNEUR, 256, 0, stream>>>(feat, mu, Wm, bias, perm, out);
    } else {
        readout_f32_strided_kernel<<<NNEUR, 256, 0, stream>>>(x, mu, Wm, bias, out);
    }
}